// Round 1
// baseline (134.424 us; speedup 1.0000x reference)
//
#include <hip/hip_runtime.h>

#define B_  4
#define S_  512
#define D_  512
#define H_  8
#define HD_ 64
#define F_  5
#define NROW (B_*S_)     // 2048
#define BHS  (B_*H_*S_)  // 16384
#define EPS_ 1e-8f

// ---------------------------------------------------------------------------
// K1: fused QKV projection GEMM.  x(2048x512) @ {Wq|Wk|Wv}(512x512) + bias
// -> q,k,v in (B,H,S,HD) layout.  64x64 tile, BK=32, 4x4 per thread.
// ---------------------------------------------------------------------------
__global__ __launch_bounds__(256) void qkv_gemm(
    const float* __restrict__ x,
    const float* __restrict__ Wq, const float* __restrict__ bq,
    const float* __restrict__ Wk, const float* __restrict__ bk,
    const float* __restrict__ Wv, const float* __restrict__ bv,
    float* __restrict__ q, float* __restrict__ k, float* __restrict__ v)
{
    const int bm = blockIdx.x;            // 0..31  (row tiles)
    const int bn = blockIdx.y;            // 0..23  (col tiles over 3*512)
    const int wsel  = (bn * 64) / D_;     // 0:q 1:k 2:v (64 | 512 so no straddle)
    const int ncol0 = (bn * 64) % D_;
    const float* __restrict__ W   = wsel==0 ? Wq : (wsel==1 ? Wk : Wv);
    const float* __restrict__ bia = wsel==0 ? bq : (wsel==1 ? bk : bv);
    float* __restrict__ out       = wsel==0 ? q  : (wsel==1 ? k  : v);

    __shared__ float As[32][68];   // k-major A tile, +4 pad (16B-aligned rows, ~4-way wr conflict)
    __shared__ float Bs[32][64];   // k-major B tile (already k-major in global)

    const int tid = threadIdx.x;
    const int tx = tid & 15, ty = tid >> 4;
    float acc[4][4] = {};

    for (int k0 = 0; k0 < D_; k0 += 32) {
#pragma unroll
        for (int l = 0; l < 2; ++l) {
            int t = tid + l*256;           // 512 float4 loads
            int row = t >> 3, c4 = t & 7;
            const float4 a = *reinterpret_cast<const float4*>(&x[(bm*64+row)*D_ + k0 + c4*4]);
            As[c4*4+0][row] = a.x;
            As[c4*4+1][row] = a.y;
            As[c4*4+2][row] = a.z;
            As[c4*4+3][row] = a.w;
        }
#pragma unroll
        for (int l = 0; l < 2; ++l) {
            int t = tid + l*256;
            int kr = t >> 4, c4 = t & 15;
            *reinterpret_cast<float4*>(&Bs[kr][c4*4]) =
                *reinterpret_cast<const float4*>(&W[(k0+kr)*D_ + ncol0 + c4*4]);
        }
        __syncthreads();
#pragma unroll
        for (int kk = 0; kk < 32; ++kk) {
            float a0[4], b0[4];
            *reinterpret_cast<float4*>(a0) = *reinterpret_cast<const float4*>(&As[kk][ty*4]);
            *reinterpret_cast<float4*>(b0) = *reinterpret_cast<const float4*>(&Bs[kk][tx*4]);
#pragma unroll
            for (int i = 0; i < 4; ++i)
#pragma unroll
                for (int j = 0; j < 4; ++j)
                    acc[i][j] = fmaf(a0[i], b0[j], acc[i][j]);
        }
        __syncthreads();
    }
    // epilogue: scatter into (B,H,S,HD)
#pragma unroll
    for (int i = 0; i < 4; ++i) {
        const int m = bm*64 + ty*4 + i;
        const int b = m >> 9, s = m & (S_-1);
#pragma unroll
        for (int j = 0; j < 4; ++j) {
            const int n  = ncol0 + tx*4 + j;
            const int h  = n >> 6, hd = n & 63;
            out[((b*H_ + h)*S_ + s)*HD_ + hd] = acc[i][j] + bia[n];
        }
    }
}

// ---------------------------------------------------------------------------
// K2: Gaussian memberships.  One wave per (b,h,s) row (64 lanes = HD dims).
// rows [0,16384) -> qm from q ; rows [16384,32768) -> km from k
// ---------------------------------------------------------------------------
__global__ __launch_bounds__(256) void membership_kernel(
    const float* __restrict__ q, const float* __restrict__ k,
    const float* __restrict__ gc, const float* __restrict__ gs,
    const float* __restrict__ gw,
    float* __restrict__ qm, float* __restrict__ km)
{
    const int row  = blockIdx.x * 4 + (threadIdx.x >> 6);
    const int lane = threadIdx.x & 63;
    const float* __restrict__ src;
    float* __restrict__ dst;
    int r;
    if (row < BHS) { src = q; dst = qm; r = row; }
    else           { src = k; dst = km; r = row - BHS; }

    const float z = src[r*HD_ + lane];
#pragma unroll
    for (int f = 0; f < F_; ++f) {
        const float nd = (z - gc[f*HD_ + lane]) / (gs[f*HD_ + lane] + EPS_);
        float p = -0.5f * nd * nd;
#pragma unroll
        for (int off = 32; off > 0; off >>= 1) p += __shfl_xor(p, off, 64);
        if (lane == 0) dst[r*F_ + f] = expf(p) * gw[f];
    }
}

// ---------------------------------------------------------------------------
// K3: fuzzy scores + row softmax -> attn (B,H,S,S) written to d_out.
// One block per (b,h, 32-row chunk); km row (512x5 f32 = 10KB) staged in LDS.
// One wave per score-row; each lane owns 8 j's.
// ---------------------------------------------------------------------------
__global__ __launch_bounds__(256) void scores_kernel(
    const float* __restrict__ qm, const float* __restrict__ km,
    const float* __restrict__ tw, float* __restrict__ attn)
{
    const int bh = blockIdx.x >> 4;        // 0..31
    const int ic = blockIdx.x & 15;        // 0..15 (32-row chunks)
    __shared__ float kms[S_ * F_];         // 10240 B
    for (int t = threadIdx.x; t < S_*F_; t += 256)
        kms[t] = km[bh*S_*F_ + t];

    // softmax of the 3 tnorm weights (redundant per-thread, trivial)
    const float t0 = tw[0], t1 = tw[1], t2 = tw[2];
    const float mx = fmaxf(t0, fmaxf(t1, t2));
    const float e0 = expf(t0-mx), e1 = expf(t1-mx), e2 = expf(t2-mx);
    const float inv3 = 1.0f / (e0+e1+e2);
    const float w0 = e0*inv3, w1 = e1*inv3, w2 = e2*inv3;
    __syncthreads();

    const int wave = threadIdx.x >> 6, lane = threadIdx.x & 63;
    for (int rr = 0; rr < 8; ++rr) {
        const int i = ic*32 + wave*8 + rr;
        const int rowbase = (bh*S_ + i)*F_;
        const float q0 = qm[rowbase+0], q1 = qm[rowbase+1], q2 = qm[rowbase+2],
                    q3 = qm[rowbase+3], q4 = qm[rowbase+4];
        float s[8];
        float m = -INFINITY;
#pragma unroll
        for (int jj = 0; jj < 8; ++jj) {
            const int j = jj*64 + lane;
            const float* kk = &kms[j*F_];
            float prod = q0*kk[0] + q1*kk[1] + q2*kk[2] + q3*kk[3] + q4*kk[4];
            float mn = fminf(q0,kk[0]) + fminf(q1,kk[1]) + fminf(q2,kk[2])
                     + fminf(q3,kk[3]) + fminf(q4,kk[4]);
            float lk = fmaxf(q0+kk[0]-1.f,0.f) + fmaxf(q1+kk[1]-1.f,0.f)
                     + fmaxf(q2+kk[2]-1.f,0.f) + fmaxf(q3+kk[3]-1.f,0.f)
                     + fmaxf(q4+kk[4]-1.f,0.f);
            s[jj] = w0*prod + w1*mn + w2*lk;
            m = fmaxf(m, s[jj]);
        }
#pragma unroll
        for (int off = 32; off > 0; off >>= 1) m = fmaxf(m, __shfl_xor(m, off, 64));
        float sum = 0.f;
        float e[8];
#pragma unroll
        for (int jj = 0; jj < 8; ++jj) { e[jj] = expf(s[jj]-m); sum += e[jj]; }
#pragma unroll
        for (int off = 32; off > 0; off >>= 1) sum += __shfl_xor(sum, off, 64);
        const float invs = 1.0f / sum;
#pragma unroll
        for (int jj = 0; jj < 8; ++jj)
            attn[(size_t)(bh*S_ + i)*S_ + jj*64 + lane] = e[jj]*invs;
    }
}

// ---------------------------------------------------------------------------
// K4: ctx = attn @ v  per (b,h).  M=512,N=64,K=512.  ctx stored (B,S,D).
// ---------------------------------------------------------------------------
__global__ __launch_bounds__(256) void av_gemm(
    const float* __restrict__ attn, const float* __restrict__ v,
    float* __restrict__ ctx)
{
    const int bh = blockIdx.x;   // 0..31
    const int bm = blockIdx.y;   // 0..7
    const float* __restrict__ A = attn + (size_t)bh*S_*S_;
    const float* __restrict__ V = v    + (size_t)bh*S_*HD_;

    __shared__ float As[32][68];
    __shared__ float Bs[32][64];
    const int tid = threadIdx.x;
    const int tx = tid & 15, ty = tid >> 4;
    float acc[4][4] = {};

    for (int k0 = 0; k0 < S_; k0 += 32) {
#pragma unroll
        for (int l = 0; l < 2; ++l) {
            int t = tid + l*256;
            int row = t >> 3, c4 = t & 7;
            const float4 a = *reinterpret_cast<const float4*>(&A[(size_t)(bm*64+row)*S_ + k0 + c4*4]);
            As[c4*4+0][row] = a.x;
            As[c4*4+1][row] = a.y;
            As[c4*4+2][row] = a.z;
            As[c4*4+3][row] = a.w;
        }
#pragma unroll
        for (int l = 0; l < 2; ++l) {
            int t = tid + l*256;
            int kr = t >> 4, c4 = t & 15;
            *reinterpret_cast<float4*>(&Bs[kr][c4*4]) =
                *reinterpret_cast<const float4*>(&V[(k0+kr)*HD_ + c4*4]);
        }
        __syncthreads();
#pragma unroll
        for (int kk = 0; kk < 32; ++kk) {
            float a0[4], b0[4];
            *reinterpret_cast<float4*>(a0) = *reinterpret_cast<const float4*>(&As[kk][ty*4]);
            *reinterpret_cast<float4*>(b0) = *reinterpret_cast<const float4*>(&Bs[kk][tx*4]);
#pragma unroll
            for (int i = 0; i < 4; ++i)
#pragma unroll
                for (int j = 0; j < 4; ++j)
                    acc[i][j] = fmaf(a0[i], b0[j], acc[i][j]);
        }
        __syncthreads();
    }
    const int b = bh >> 3, h = bh & 7;
#pragma unroll
    for (int i = 0; i < 4; ++i) {
        const int s = bm*64 + ty*4 + i;
#pragma unroll
        for (int j = 0; j < 4; ++j) {
            const int hd = tx*4 + j;
            ctx[((size_t)(b*S_ + s))*D_ + h*HD_ + hd] = acc[i][j];
        }
    }
}

// ---------------------------------------------------------------------------
// K5: out = ctx(2048x512) @ Wo + bo  (row-major output into d_out[0:1M])
// ---------------------------------------------------------------------------
__global__ __launch_bounds__(256) void out_gemm(
    const float* __restrict__ Ag, const float* __restrict__ W,
    const float* __restrict__ bias, float* __restrict__ out)
{
    const int bm = blockIdx.x;   // 0..31
    const int bn = blockIdx.y;   // 0..7
    __shared__ float As[32][68];
    __shared__ float Bs[32][64];
    const int tid = threadIdx.x;
    const int tx = tid & 15, ty = tid >> 4;
    float acc[4][4] = {};

    for (int k0 = 0; k0 < D_; k0 += 32) {
#pragma unroll
        for (int l = 0; l < 2; ++l) {
            int t = tid + l*256;
            int row = t >> 3, c4 = t & 7;
            const float4 a = *reinterpret_cast<const float4*>(&Ag[(size_t)(bm*64+row)*D_ + k0 + c4*4]);
            As[c4*4+0][row] = a.x;
            As[c4*4+1][row] = a.y;
            As[c4*4+2][row] = a.z;
            As[c4*4+3][row] = a.w;
        }
#pragma unroll
        for (int l = 0; l < 2; ++l) {
            int t = tid + l*256;
            int kr = t >> 4, c4 = t & 15;
            *reinterpret_cast<float4*>(&Bs[kr][c4*4]) =
                *reinterpret_cast<const float4*>(&W[(k0+kr)*D_ + bn*64 + c4*4]);
        }
        __syncthreads();
#pragma unroll
        for (int kk = 0; kk < 32; ++kk) {
            float a0[4], b0[4];
            *reinterpret_cast<float4*>(a0) = *reinterpret_cast<const float4*>(&As[kk][ty*4]);
            *reinterpret_cast<float4*>(b0) = *reinterpret_cast<const float4*>(&Bs[kk][tx*4]);
#pragma unroll
            for (int i = 0; i < 4; ++i)
#pragma unroll
                for (int j = 0; j < 4; ++j)
                    acc[i][j] = fmaf(a0[i], b0[j], acc[i][j]);
        }
        __syncthreads();
    }
#pragma unroll
    for (int i = 0; i < 4; ++i) {
        const int m = bm*64 + ty*4 + i;
#pragma unroll
        for (int j = 0; j < 4; ++j) {
            const int n = bn*64 + tx*4 + j;
            out[(size_t)m*D_ + n] = acc[i][j] + bias[n];
        }
    }
}

// ---------------------------------------------------------------------------
extern "C" void kernel_launch(void* const* d_in, const int* in_sizes, int n_in,
                              void* d_out, int out_size, void* d_ws, size_t ws_size,
                              hipStream_t stream)
{
    const float* x  = (const float*)d_in[0];
    const float* Wq = (const float*)d_in[1];
    const float* bq = (const float*)d_in[2];
    const float* Wk = (const float*)d_in[3];
    const float* bk = (const float*)d_in[4];
    const float* Wv = (const float*)d_in[5];
    const float* bv = (const float*)d_in[6];
    const float* Wo = (const float*)d_in[7];
    const float* bo = (const float*)d_in[8];
    const float* gc = (const float*)d_in[9];
    const float* gs = (const float*)d_in[10];
    const float* gw = (const float*)d_in[11];
    const float* tw = (const float*)d_in[12];

    float* ws = (float*)d_ws;
    float* q   = ws;                      // 1,048,576 f32 (aliased by ctx later)
    float* k   = q  + (size_t)B_*H_*S_*HD_;
    float* v   = k  + (size_t)B_*H_*S_*HD_;
    float* qm  = v  + (size_t)B_*H_*S_*HD_;  // 81,920 f32
    float* km  = qm + (size_t)BHS*F_;
    float* ctx = q;                       // q dead after membership -> reuse

    float* out0 = (float*)d_out;                        // (B,S,D)
    float* attn = out0 + (size_t)B_*S_*D_;              // (B,H,S,S)

    qkv_gemm<<<dim3(32, 24), 256, 0, stream>>>(x, Wq, bq, Wk, bk, Wv, bv, q, k, v);
    membership_kernel<<<(2*BHS)/4, 256, 0, stream>>>(q, k, gc, gs, gw, qm, km);
    scores_kernel<<<B_*H_*(S_/32), 256, 0, stream>>>(qm, km, tw, attn);
    av_gemm<<<dim3(B_*H_, S_/64), 256, 0, stream>>>(attn, v, ctx);
    out_gemm<<<dim3(NROW/64, D_/64), 256, 0, stream>>>(ctx, Wo, bo, out0);
}

// Round 2
// 90.942 us; speedup vs baseline: 1.4781x; 1.4781x over previous
//
#include <hip/hip_runtime.h>
#include <hip/hip_bf16.h>

#define B_  4
#define S_  512
#define D_  512
#define H_  8
#define HD_ 64
#define F_  5
#define NROW (B_*S_)     // 2048
#define BHS  (B_*H_*S_)  // 16384
#define EPS_ 1e-8f

typedef __attribute__((ext_vector_type(8))) short bf16x8;
typedef __attribute__((ext_vector_type(4))) float f32x4;

static __device__ __forceinline__ short f2bf(float f) {
    __hip_bfloat16 h = __float2bfloat16(f);
    return *reinterpret_cast<short*>(&h);
}

// async global->LDS, 16B per lane; dest = ldsbase + lane*16 (wave-linear)
#define GLOAD16(ldsp, gp) \
    __builtin_amdgcn_global_load_lds( \
        (const __attribute__((address_space(1))) unsigned int*)(gp), \
        (__attribute__((address_space(3))) unsigned int*)(ldsp), 16, 0, 0)

// ---------------------------------------------------------------------------
// C1: x (f32) -> xb (bf16), same layout
// ---------------------------------------------------------------------------
__global__ __launch_bounds__(256) void convert_x(
    const float* __restrict__ in, short* __restrict__ out, int n4)
{
    int i = blockIdx.x * 256 + threadIdx.x;
    if (i < n4) {
        float4 f = reinterpret_cast<const float4*>(in)[i];
        short4 o;
        o.x = f2bf(f.x); o.y = f2bf(f.y); o.z = f2bf(f.z); o.w = f2bf(f.w);
        reinterpret_cast<short4*>(out)[i] = o;
    }
}

// ---------------------------------------------------------------------------
// C2: Wq/Wk/Wv/Wo (512x512 f32, k-major) -> transposed bf16 (n-major):
//     WqkvT[1536][512] (rows 0-511=WqT, 512-1023=WkT, 1024-1535=WvT), WoT[512][512]
// ---------------------------------------------------------------------------
__global__ __launch_bounds__(256) void convert_wt(
    const float* __restrict__ Wq, const float* __restrict__ Wk,
    const float* __restrict__ Wv, const float* __restrict__ Wo,
    short* __restrict__ WqkvT, short* __restrict__ WoT)
{
    const int widx = blockIdx.x >> 6;          // 0..3
    const int tile = blockIdx.x & 63;          // 8x8 tiles of 64x64
    const int k0 = (tile >> 3) * 64, n0 = (tile & 7) * 64;
    const float* __restrict__ src = widx==0?Wq:(widx==1?Wk:(widx==2?Wv:Wo));
    short* __restrict__ dst = (widx < 3) ? WqkvT : WoT;
    const int drow0 = (widx < 3) ? widx * 512 : 0;

    __shared__ short T[64][72];
    const int t = threadIdx.x;
    const int r = t >> 2, qq = t & 3;
#pragma unroll
    for (int i = 0; i < 4; ++i) {
        float4 f = *reinterpret_cast<const float4*>(&src[(k0+r)*D_ + n0 + qq*16 + i*4]);
        T[r][qq*16+i*4+0] = f2bf(f.x);
        T[r][qq*16+i*4+1] = f2bf(f.y);
        T[r][qq*16+i*4+2] = f2bf(f.z);
        T[r][qq*16+i*4+3] = f2bf(f.w);
    }
    __syncthreads();
    const int c = t >> 2;                       // local n
#pragma unroll
    for (int i = 0; i < 4; ++i) {
        short4 o;
        o.x = T[qq*16+i*4+0][c];
        o.y = T[qq*16+i*4+1][c];
        o.z = T[qq*16+i*4+2][c];
        o.w = T[qq*16+i*4+3][c];
        *reinterpret_cast<short4*>(&dst[(size_t)(drow0+n0+c)*512 + k0 + qq*16 + i*4]) = o;
    }
}

// ---------------------------------------------------------------------------
// K1: QKV MFMA GEMM.  xb(2048x512) @ WqkvT -> q,k,v f32 (B,H,S,HD) + bias.
// 128x128 tile, BK=64, 4 waves (2x2), each wave 64x64 = 4x4 16x16 frags.
// ---------------------------------------------------------------------------
__global__ __launch_bounds__(256) void qkv_mfma(
    const short* __restrict__ Ab, const short* __restrict__ BT,
    const float* __restrict__ bq, const float* __restrict__ bk,
    const float* __restrict__ bv,
    float* __restrict__ q, float* __restrict__ k, float* __restrict__ v)
{
    __shared__ short As[128*64];   // [m][k] 16KB
    __shared__ short Bs[128*64];   // [n][k] 16KB
    const int tid = threadIdx.x;
    const int wid = tid >> 6, lane = tid & 63;
    const int wr = wid >> 1, wc = wid & 1;
    const int m0 = blockIdx.x * 128, n0 = blockIdx.y * 128;

    f32x4 acc[4][4] = {};

    for (int k0 = 0; k0 < 512; k0 += 64) {
#pragma unroll
        for (int i = 0; i < 4; ++i) {
            const int c = wid*4 + i;                 // chunk 0..15 (1KB each)
            const int row = c*8 + (lane >> 3);
            const int kk  = (lane & 7) * 8;
            GLOAD16(&As[c*512], &Ab[(size_t)(m0+row)*512 + k0 + kk]);
            GLOAD16(&Bs[c*512], &BT[(size_t)(n0+row)*512 + k0 + kk]);
        }
        asm volatile("s_waitcnt vmcnt(0)" ::: "memory");
        __syncthreads();
#pragma unroll
        for (int ks = 0; ks < 2; ++ks) {
            bf16x8 a[4], b[4];
#pragma unroll
            for (int f = 0; f < 4; ++f) {
                const int ar = wr*64 + f*16 + (lane & 15);
                a[f] = *reinterpret_cast<const bf16x8*>(&As[ar*64 + ks*32 + (lane>>4)*8]);
                const int br = wc*64 + f*16 + (lane & 15);
                b[f] = *reinterpret_cast<const bf16x8*>(&Bs[br*64 + ks*32 + (lane>>4)*8]);
            }
#pragma unroll
            for (int i = 0; i < 4; ++i)
#pragma unroll
                for (int j = 0; j < 4; ++j)
                    acc[i][j] = __builtin_amdgcn_mfma_f32_16x16x32_bf16(a[i], b[j], acc[i][j], 0, 0, 0);
        }
        __syncthreads();
    }

    const int wsel = n0 >> 9;
    const float* __restrict__ bias = wsel==0 ? bq : (wsel==1 ? bk : bv);
    float* __restrict__ dst = wsel==0 ? q : (wsel==1 ? k : v);
    const int nl0 = n0 & 511;
#pragma unroll
    for (int i = 0; i < 4; ++i)
#pragma unroll
        for (int j = 0; j < 4; ++j)
#pragma unroll
            for (int r = 0; r < 4; ++r) {
                const int m = m0 + wr*64 + i*16 + (lane>>4)*4 + r;
                const int n = nl0 + wc*64 + j*16 + (lane & 15);
                const int b_ = m >> 9, s = m & 511;
                const int h = n >> 6, hd = n & 63;
                dst[((size_t)((b_*H_ + h)*S_ + s))*HD_ + hd] = acc[i][j][r] + bias[n];
            }
}

// ---------------------------------------------------------------------------
// K2: Gaussian memberships (unchanged; reads f32 q,k)
// ---------------------------------------------------------------------------
__global__ __launch_bounds__(256) void membership_kernel(
    const float* __restrict__ q, const float* __restrict__ k,
    const float* __restrict__ gc, const float* __restrict__ gs,
    const float* __restrict__ gw,
    float* __restrict__ qm, float* __restrict__ km)
{
    const int row  = blockIdx.x * 4 + (threadIdx.x >> 6);
    const int lane = threadIdx.x & 63;
    const float* __restrict__ src;
    float* __restrict__ dst;
    int r;
    if (row < BHS) { src = q; dst = qm; r = row; }
    else           { src = k; dst = km; r = row - BHS; }

    const float z = src[r*HD_ + lane];
#pragma unroll
    for (int f = 0; f < F_; ++f) {
        const float nd = (z - gc[f*HD_ + lane]) / (gs[f*HD_ + lane] + EPS_);
        float p = -0.5f * nd * nd;
#pragma unroll
        for (int off = 32; off > 0; off >>= 1) p += __shfl_xor(p, off, 64);
        if (lane == 0) dst[r*F_ + f] = expf(p) * gw[f];
    }
}

// ---------------------------------------------------------------------------
// T1: v f32 (BH,S,HD) -> vT bf16 (BH,HD,S)
// ---------------------------------------------------------------------------
__global__ __launch_bounds__(256) void transpose_v(
    const float* __restrict__ v, short* __restrict__ vT)
{
    const int bh = blockIdx.x, s0 = blockIdx.y * 64;
    __shared__ short T[64][72];
    const int t = threadIdx.x;
    const int r = t >> 2, qq = t & 3;
#pragma unroll
    for (int i = 0; i < 4; ++i) {
        float4 f = *reinterpret_cast<const float4*>(&v[((size_t)bh*S_ + s0 + r)*HD_ + qq*16 + i*4]);
        T[r][qq*16+i*4+0] = f2bf(f.x);
        T[r][qq*16+i*4+1] = f2bf(f.y);
        T[r][qq*16+i*4+2] = f2bf(f.z);
        T[r][qq*16+i*4+3] = f2bf(f.w);
    }
    __syncthreads();
    const int c = t >> 2;                       // local hd
#pragma unroll
    for (int i = 0; i < 4; ++i) {
        short4 o;
        o.x = T[qq*16+i*4+0][c];
        o.y = T[qq*16+i*4+1][c];
        o.z = T[qq*16+i*4+2][c];
        o.w = T[qq*16+i*4+3][c];
        *reinterpret_cast<short4*>(&vT[((size_t)bh*HD_ + c)*S_ + s0 + qq*16 + i*4]) = o;
    }
}

// ---------------------------------------------------------------------------
// K3: fuzzy scores + row softmax -> attn f32 (unchanged)
// ---------------------------------------------------------------------------
__global__ __launch_bounds__(256) void scores_kernel(
    const float* __restrict__ qm, const float* __restrict__ km,
    const float* __restrict__ tw, float* __restrict__ attn)
{
    const int bh = blockIdx.x >> 4;
    const int ic = blockIdx.x & 15;
    __shared__ float kms[S_ * F_];
    for (int t = threadIdx.x; t < S_*F_; t += 256)
        kms[t] = km[bh*S_*F_ + t];

    const float t0 = tw[0], t1 = tw[1], t2 = tw[2];
    const float mx = fmaxf(t0, fmaxf(t1, t2));
    const float e0 = expf(t0-mx), e1 = expf(t1-mx), e2 = expf(t2-mx);
    const float inv3 = 1.0f / (e0+e1+e2);
    const float w0 = e0*inv3, w1 = e1*inv3, w2 = e2*inv3;
    __syncthreads();

    const int wave = threadIdx.x >> 6, lane = threadIdx.x & 63;
    for (int rr = 0; rr < 8; ++rr) {
        const int i = ic*32 + wave*8 + rr;
        const int rowbase = (bh*S_ + i)*F_;
        const float q0 = qm[rowbase+0], q1 = qm[rowbase+1], q2 = qm[rowbase+2],
                    q3 = qm[rowbase+3], q4 = qm[rowbase+4];
        float s[8];
        float m = -INFINITY;
#pragma unroll
        for (int jj = 0; jj < 8; ++jj) {
            const int j = jj*64 + lane;
            const float* kk = &kms[j*F_];
            float prod = q0*kk[0] + q1*kk[1] + q2*kk[2] + q3*kk[3] + q4*kk[4];
            float mn = fminf(q0,kk[0]) + fminf(q1,kk[1]) + fminf(q2,kk[2])
                     + fminf(q3,kk[3]) + fminf(q4,kk[4]);
            float lk = fmaxf(q0+kk[0]-1.f,0.f) + fmaxf(q1+kk[1]-1.f,0.f)
                     + fmaxf(q2+kk[2]-1.f,0.f) + fmaxf(q3+kk[3]-1.f,0.f)
                     + fmaxf(q4+kk[4]-1.f,0.f);
            s[jj] = w0*prod + w1*mn + w2*lk;
            m = fmaxf(m, s[jj]);
        }
#pragma unroll
        for (int off = 32; off > 0; off >>= 1) m = fmaxf(m, __shfl_xor(m, off, 64));
        float sum = 0.f;
        float e[8];
#pragma unroll
        for (int jj = 0; jj < 8; ++jj) { e[jj] = expf(s[jj]-m); sum += e[jj]; }
#pragma unroll
        for (int off = 32; off > 0; off >>= 1) sum += __shfl_xor(sum, off, 64);
        const float invs = 1.0f / sum;
#pragma unroll
        for (int jj = 0; jj < 8; ++jj)
            attn[(size_t)(bh*S_ + i)*S_ + jj*64 + lane] = e[jj]*invs;
    }
}

// ---------------------------------------------------------------------------
// K4: ctx = attn @ v per bh.  64x64 tile, BK=64, 4 waves (2x2), wave 32x32.
// A = attn f32 (reg-stage + convert), B = vT bf16 (global_load_lds).
// ---------------------------------------------------------------------------
__global__ __launch_bounds__(256) void av_mfma(
    const float* __restrict__ attn, const short* __restrict__ vT,
    float* __restrict__ ctx)
{
    const int m0 = blockIdx.x * 64;
    const int bh = blockIdx.y;
    const float* __restrict__ Af = attn + (size_t)bh*S_*S_;
    const short* __restrict__ Bv = vT   + (size_t)bh*HD_*S_;

    __shared__ short As[64*64];   // [m][k] 8KB
    __shared__ short Bs[64*64];   // [n=hd][k=s] 8KB
    const int tid = threadIdx.x;
    const int wid = tid >> 6, lane = tid & 63;
    const int wr = wid >> 1, wc = wid & 1;

    f32x4 acc[2][2] = {};

    for (int k0 = 0; k0 < S_; k0 += 64) {
        // B: async (8 chunks of 1KB, 2 per wave)
#pragma unroll
        for (int i = 0; i < 2; ++i) {
            const int c = wid*2 + i;
            const int row = c*8 + (lane >> 3);
            const int kk  = (lane & 7) * 8;
            GLOAD16(&Bs[c*512], &Bv[(size_t)row*S_ + k0 + kk]);
        }
        // A: reg-stage f32 -> bf16, linear 16B ds_writes (conflict-free)
#pragma unroll
        for (int hf = 0; hf < 2; ++hf) {
            const int tt = tid + hf*256;                  // chunk index
            const int row = tt >> 3, kk = (tt & 7) * 8;
            const float* p = &Af[(size_t)(m0+row)*S_ + k0 + kk];
            float4 fa = *reinterpret_cast<const float4*>(p);
            float4 fb = *reinterpret_cast<const float4*>(p+4);
            bf16x8 pk;
            pk[0]=f2bf(fa.x); pk[1]=f2bf(fa.y); pk[2]=f2bf(fa.z); pk[3]=f2bf(fa.w);
            pk[4]=f2bf(fb.x); pk[5]=f2bf(fb.y); pk[6]=f2bf(fb.z); pk[7]=f2bf(fb.w);
            *reinterpret_cast<bf16x8*>(&As[tt*8]) = pk;
        }
        asm volatile("s_waitcnt vmcnt(0)" ::: "memory");
        __syncthreads();
#pragma unroll
        for (int ks = 0; ks < 2; ++ks) {
            bf16x8 a[2], b[2];
#pragma unroll
            for (int f = 0; f < 2; ++f) {
                const int ar = wr*32 + f*16 + (lane & 15);
                a[f] = *reinterpret_cast<const bf16x8*>(&As[ar*64 + ks*32 + (lane>>4)*8]);
                const int br = wc*32 + f*16 + (lane & 15);
                b[f] = *reinterpret_cast<const bf16x8*>(&Bs[br*64 + ks*32 + (lane>>4)*8]);
            }
#pragma unroll
            for (int i = 0; i < 2; ++i)
#pragma unroll
                for (int j = 0; j < 2; ++j)
                    acc[i][j] = __builtin_amdgcn_mfma_f32_16x16x32_bf16(a[i], b[j], acc[i][j], 0, 0, 0);
        }
        __syncthreads();
    }
    const int b_ = bh >> 3, h = bh & 7;
#pragma unroll
    for (int i = 0; i < 2; ++i)
#pragma unroll
        for (int j = 0; j < 2; ++j)
#pragma unroll
            for (int r = 0; r < 4; ++r) {
                const int s = m0 + wr*32 + i*16 + (lane>>4)*4 + r;
                const int hd = wc*32 + j*16 + (lane & 15);
                ctx[((size_t)(b_*S_ + s))*D_ + h*HD_ + hd] = acc[i][j][r];
            }
}

// ---------------------------------------------------------------------------
// K5: out = ctx(2048x512) @ Wo + bo.  64x64 tile, same structure as K4.
// A = ctx f32 (reg-stage + convert), B = WoT bf16 (global_load_lds).
// ---------------------------------------------------------------------------
__global__ __launch_bounds__(256) void out_mfma(
    const float* __restrict__ ctx, const short* __restrict__ WoT,
    const float* __restrict__ bo, float* __restrict__ out)
{
    const int m0 = blockIdx.x * 64;
    const int n0 = blockIdx.y * 64;

    __shared__ short As[64*64];
    __shared__ short Bs[64*64];
    const int tid = threadIdx.x;
    const int wid = tid >> 6, lane = tid & 63;
    const int wr = wid >> 1, wc = wid & 1;

    f32x4 acc[2][2] = {};

    for (int k0 = 0; k0 < D_; k0 += 64) {
#pragma unroll
        for (int i = 0; i < 2; ++i) {
            const int c = wid*2 + i;
            const int row = c*8 + (lane >> 3);
            const int kk  = (lane & 7) * 8;
            GLOAD16(&Bs[c*512], &WoT[(size_t)(n0+row)*D_ + k0 + kk]);
        }
#pragma unroll
        for (int hf = 0; hf < 2; ++hf) {
            const int tt = tid + hf*256;
            const int row = tt >> 3, kk = (tt & 7) * 8;
            const float* p = &ctx[(size_t)(m0+row)*D_ + k0 + kk];
            float4 fa = *reinterpret_cast<const float4*>(p);
            float4 fb = *reinterpret_cast<const float4*>(p+4);
            bf16x8 pk;
            pk[0]=f2bf(fa.x); pk[1]=f2bf(fa.y); pk[2]=f2bf(fa.z); pk[3]=f2bf(fa.w);
            pk[4]=f2bf(fb.x); pk[5]=f2bf(fb.y); pk[6]=f2bf(fb.z); pk[7]=f2bf(fb.w);
            *reinterpret_cast<bf16x8*>(&As[tt*8]) = pk;
        }
        asm volatile("s_waitcnt vmcnt(0)" ::: "memory");
        __syncthreads();
#pragma unroll
        for (int ks = 0; ks < 2; ++ks) {
            bf16x8 a[2], b[2];
#pragma unroll
            for (int f = 0; f < 2; ++f) {
                const int ar = wr*32 + f*16 + (lane & 15);
                a[f] = *reinterpret_cast<const bf16x8*>(&As[ar*64 + ks*32 + (lane>>4)*8]);
                const int br = wc*32 + f*16 + (lane & 15);
                b[f] = *reinterpret_cast<const bf16x8*>(&Bs[br*64 + ks*32 + (lane>>4)*8]);
            }
#pragma unroll
            for (int i = 0; i < 2; ++i)
#pragma unroll
                for (int j = 0; j < 2; ++j)
                    acc[i][j] = __builtin_amdgcn_mfma_f32_16x16x32_bf16(a[i], b[j], acc[i][j], 0, 0, 0);
        }
        __syncthreads();
    }
#pragma unroll
    for (int i = 0; i < 2; ++i)
#pragma unroll
        for (int j = 0; j < 2; ++j)
#pragma unroll
            for (int r = 0; r < 4; ++r) {
                const int m = m0 + wr*32 + i*16 + (lane>>4)*4 + r;
                const int n = n0 + wc*32 + j*16 + (lane & 15);
                out[(size_t)m*D_ + n] = acc[i][j][r] + bo[n];
            }
}

// ---------------------------------------------------------------------------
extern "C" void kernel_launch(void* const* d_in, const int* in_sizes, int n_in,
                              void* d_out, int out_size, void* d_ws, size_t ws_size,
                              hipStream_t stream)
{
    const float* x  = (const float*)d_in[0];
    const float* Wq = (const float*)d_in[1];
    const float* bq = (const float*)d_in[2];
    const float* Wk = (const float*)d_in[3];
    const float* bk = (const float*)d_in[4];
    const float* Wv = (const float*)d_in[5];
    const float* bv = (const float*)d_in[6];
    const float* Wo = (const float*)d_in[7];
    const float* bo = (const float*)d_in[8];
    const float* gc = (const float*)d_in[9];
    const float* gs = (const float*)d_in[10];
    const float* gw = (const float*)d_in[11];
    const float* tw = (const float*)d_in[12];

    float* ws = (float*)d_ws;
    float* q  = ws;                                   // 1M f32
    float* k  = q + 1048576;                          // 1M f32
    float* v  = k + 1048576;                          // 1M f32
    short* xb    = (short*)(v + 1048576);             // 1M bf16 (2MB)
    short* WqkvT = xb + 1048576;                      // 786432 bf16
    short* WoT   = WqkvT + 786432;                    // 262144 bf16
    float* qm    = (float*)xb;                        // alias xb (dead after qkv): 81920 f32
    float* km    = qm + 81920;                        //  + 81920 f32  (< 2MB: fits)
    short* vT    = (short*)q;                         // alias q (dead after membership)
    float* ctx   = k;                                 // alias k (dead after membership)

    float* out0 = (float*)d_out;                      // (B,S,D)
    float* attn = out0 + (size_t)B_*S_*D_;            // (B,H,S,S)

    convert_x<<<1024, 256, 0, stream>>>(x, xb, (NROW*D_)/4);
    convert_wt<<<256, 256, 0, stream>>>(Wq, Wk, Wv, Wo, WqkvT, WoT);
    qkv_mfma<<<dim3(NROW/128, 1536/128), 256, 0, stream>>>(xb, WqkvT, bq, bk, bv, q, k, v);
    membership_kernel<<<(2*BHS)/4, 256, 0, stream>>>(q, k, gc, gs, gw, qm, km);
    transpose_v<<<dim3(B_*H_, S_/64), 256, 0, stream>>>(v, vT);
    scores_kernel<<<B_*H_*(S_/32), 256, 0, stream>>>(qm, km, tw, attn);
    av_mfma<<<dim3(S_/64, B_*H_), 256, 0, stream>>>(attn, vT, ctx);
    out_mfma<<<dim3(NROW/64, D_/64), 256, 0, stream>>>(ctx, WoT, bo, out0);
}

// Round 3
// 77.051 us; speedup vs baseline: 1.7446x; 1.1803x over previous
//
#include <hip/hip_runtime.h>
#include <hip/hip_bf16.h>

#define B_  4
#define S_  512
#define D_  512
#define H_  8
#define HD_ 64
#define F_  5
#define NROW (B_*S_)     // 2048
#define BHS  (B_*H_*S_)  // 16384
#define EPS_ 1e-8f

typedef __attribute__((ext_vector_type(8))) short bf16x8;
typedef __attribute__((ext_vector_type(4))) float f32x4;

static __device__ __forceinline__ short f2bf(float f) {
    __hip_bfloat16 h = __float2bfloat16(f);
    return *reinterpret_cast<short*>(&h);
}

// async global->LDS, 16B per lane; dest = ldsbase + lane*16 (wave-linear)
#define GLOAD16(ldsp, gp) \
    __builtin_amdgcn_global_load_lds( \
        (const __attribute__((address_space(1))) unsigned int*)(gp), \
        (__attribute__((address_space(3))) unsigned int*)(ldsp), 16, 0, 0)

// ---------------------------------------------------------------------------
// C1: merged conversions.
//   blocks [0,1024):   x f32 -> xb bf16 (same layout)
//   blocks [1024,1280): Wq/Wk/Wv/Wo f32 (k-major) -> WqkvT[1536][512] /
//                       WoT[512][512] bf16 (n-major)
// ---------------------------------------------------------------------------
__global__ __launch_bounds__(256) void convert_fused(
    const float* __restrict__ x,
    const float* __restrict__ Wq, const float* __restrict__ Wk,
    const float* __restrict__ Wv, const float* __restrict__ Wo,
    short* __restrict__ xb, short* __restrict__ WqkvT, short* __restrict__ WoT)
{
    const int bid = blockIdx.x;
    if (bid < 1024) {
        int i = bid * 256 + threadIdx.x;          // 262144 float4s exactly
        float4 f = reinterpret_cast<const float4*>(x)[i];
        short4 o;
        o.x = f2bf(f.x); o.y = f2bf(f.y); o.z = f2bf(f.z); o.w = f2bf(f.w);
        reinterpret_cast<short4*>(xb)[i] = o;
        return;
    }
    const int wb = bid - 1024;
    const int widx = wb >> 6;                  // 0..3
    const int tile = wb & 63;                  // 8x8 tiles of 64x64
    const int k0 = (tile >> 3) * 64, n0 = (tile & 7) * 64;
    const float* __restrict__ src = widx==0?Wq:(widx==1?Wk:(widx==2?Wv:Wo));
    short* __restrict__ dst = (widx < 3) ? WqkvT : WoT;
    const int drow0 = (widx < 3) ? widx * 512 : 0;

    __shared__ short T[64][72];
    const int t = threadIdx.x;
    const int r = t >> 2, qq = t & 3;
#pragma unroll
    for (int i = 0; i < 4; ++i) {
        float4 f = *reinterpret_cast<const float4*>(&src[(k0+r)*D_ + n0 + qq*16 + i*4]);
        T[r][qq*16+i*4+0] = f2bf(f.x);
        T[r][qq*16+i*4+1] = f2bf(f.y);
        T[r][qq*16+i*4+2] = f2bf(f.z);
        T[r][qq*16+i*4+3] = f2bf(f.w);
    }
    __syncthreads();
    const int c = t >> 2;                       // local n
#pragma unroll
    for (int i = 0; i < 4; ++i) {
        short4 o;
        o.x = T[qq*16+i*4+0][c];
        o.y = T[qq*16+i*4+1][c];
        o.z = T[qq*16+i*4+2][c];
        o.w = T[qq*16+i*4+3][c];
        *reinterpret_cast<short4*>(&dst[(size_t)(drow0+n0+c)*512 + k0 + qq*16 + i*4]) = o;
    }
}

// ---------------------------------------------------------------------------
// K1: QKV MFMA GEMM + fused membership (q,k) + fused vT write (v).
// xb(2048x512) @ WqkvT(1536x512 n-major).  128x128 tile, BK=64, 4 waves.
// q/k tiles: membership -> qm/km (B*H*S,5); v tiles: bf16 vT (BH,HD,S).
// No q/k/v f32 tensors ever touch global memory.
// ---------------------------------------------------------------------------
__global__ __launch_bounds__(256) void qkv_mfma(
    const short* __restrict__ Ab, const short* __restrict__ BT,
    const float* __restrict__ bq, const float* __restrict__ bk,
    const float* __restrict__ bv,
    const float* __restrict__ gc, const float* __restrict__ gs,
    const float* __restrict__ gw,
    float* __restrict__ qm, float* __restrict__ km, short* __restrict__ vT)
{
    __shared__ short As[128*64];   // [m][k] 16KB
    __shared__ short Bs[128*64];   // [n][k] 16KB
    const int tid = threadIdx.x;
    const int wid = tid >> 6, lane = tid & 63;
    const int wr = wid >> 1, wc = wid & 1;
    const int m0 = blockIdx.x * 128, n0 = blockIdx.y * 128;

    f32x4 acc[4][4] = {};

    for (int k0 = 0; k0 < 512; k0 += 64) {
#pragma unroll
        for (int i = 0; i < 4; ++i) {
            const int c = wid*4 + i;                 // chunk 0..15 (1KB each)
            const int row = c*8 + (lane >> 3);
            const int kk  = (lane & 7) * 8;
            GLOAD16(&As[c*512], &Ab[(size_t)(m0+row)*512 + k0 + kk]);
            GLOAD16(&Bs[c*512], &BT[(size_t)(n0+row)*512 + k0 + kk]);
        }
        asm volatile("s_waitcnt vmcnt(0)" ::: "memory");
        __syncthreads();
#pragma unroll
        for (int ks = 0; ks < 2; ++ks) {
            bf16x8 a[4], b[4];
#pragma unroll
            for (int f = 0; f < 4; ++f) {
                const int ar = wr*64 + f*16 + (lane & 15);
                a[f] = *reinterpret_cast<const bf16x8*>(&As[ar*64 + ks*32 + (lane>>4)*8]);
                const int br = wc*64 + f*16 + (lane & 15);
                b[f] = *reinterpret_cast<const bf16x8*>(&Bs[br*64 + ks*32 + (lane>>4)*8]);
            }
#pragma unroll
            for (int i = 0; i < 4; ++i)
#pragma unroll
                for (int j = 0; j < 4; ++j)
                    acc[i][j] = __builtin_amdgcn_mfma_f32_16x16x32_bf16(a[i], b[j], acc[i][j], 0, 0, 0);
        }
        __syncthreads();
    }

    const int wsel = n0 >> 9;              // 0:q 1:k 2:v
    const int h = ((n0 & 511) >> 6) + wc;  // head this wave owns (64 cols)
    const int b_ = m0 >> 9;                // batch (128-tile never straddles)
    const int bh = b_*H_ + h;
    const int hdl = lane & 15;

    if (wsel < 2) {
        // ---- fused Gaussian membership ----
        const float* __restrict__ bias = wsel==0 ? bq : bk;
        float* __restrict__ dst        = wsel==0 ? qm : km;
        float gcv[F_][4], isv[F_][4], bi4[4];
#pragma unroll
        for (int f = 0; f < F_; ++f)
#pragma unroll
            for (int j = 0; j < 4; ++j) {
                const int hd = j*16 + hdl;
                gcv[f][j] = gc[f*HD_ + hd];
                isv[f][j] = 1.0f / (gs[f*HD_ + hd] + EPS_);
            }
#pragma unroll
        for (int j = 0; j < 4; ++j) bi4[j] = bias[h*64 + j*16 + hdl];
        float gwv[F_];
#pragma unroll
        for (int f = 0; f < F_; ++f) gwv[f] = gw[f];

#pragma unroll
        for (int i = 0; i < 4; ++i)
#pragma unroll
            for (int r = 0; r < 4; ++r) {
                float z[4];
#pragma unroll
                for (int j = 0; j < 4; ++j) z[j] = acc[i][j][r] + bi4[j];
                float p[F_];
#pragma unroll
                for (int f = 0; f < F_; ++f) {
                    float t = 0.f;
#pragma unroll
                    for (int j = 0; j < 4; ++j) {
                        const float nd = (z[j] - gcv[f][j]) * isv[f][j];
                        t = fmaf(nd*nd, -0.5f, t);
                    }
                    p[f] = t;
                }
#pragma unroll
                for (int off = 1; off < 16; off <<= 1)
#pragma unroll
                    for (int f = 0; f < F_; ++f) p[f] += __shfl_xor(p[f], off, 64);
                if (hdl == 0) {
                    const int m = m0 + wr*64 + i*16 + (lane>>4)*4 + r;
                    const int s = m & 511;
                    float* o = &dst[((size_t)bh*S_ + s)*F_];
#pragma unroll
                    for (int f = 0; f < F_; ++f) o[f] = expf(p[f]) * gwv[f];
                }
            }
    } else {
        // ---- fused V transpose: vT[bh][hd][s] bf16 ----
        float bi4[4];
#pragma unroll
        for (int j = 0; j < 4; ++j) bi4[j] = bv[h*64 + j*16 + hdl];
#pragma unroll
        for (int i = 0; i < 4; ++i)
#pragma unroll
            for (int j = 0; j < 4; ++j) {
                short4 o;
                o.x = f2bf(acc[i][j][0] + bi4[j]);
                o.y = f2bf(acc[i][j][1] + bi4[j]);
                o.z = f2bf(acc[i][j][2] + bi4[j]);
                o.w = f2bf(acc[i][j][3] + bi4[j]);
                const int sb = (m0 & 511) + wr*64 + i*16 + (lane>>4)*4;
                *reinterpret_cast<short4*>(
                    &vT[((size_t)bh*HD_ + j*16 + hdl)*S_ + sb]) = o;
            }
    }
}

// ---------------------------------------------------------------------------
// K2: fused scores + softmax + attn-write + PV MFMA.
// Block = (bh, 64-row tile), 4 waves, 16 rows/wave in score phase.
// km in registers (lane-invariant across rows); P in 64KB XOR-swizzled LDS;
// V read directly from global (L1/L2-resident, 64KB/bh).
// ---------------------------------------------------------------------------
__global__ __launch_bounds__(256) void scores_av(
    const float* __restrict__ qm, const float* __restrict__ km,
    const float* __restrict__ tw, const short* __restrict__ vT,
    float* __restrict__ attn, float* __restrict__ ctx)
{
    __shared__ short P[64*512];            // 64KB, [row][j] with byte^=(row&7)<<4
    const int s0 = blockIdx.x * 64;
    const int bh = blockIdx.y;
    const int tid = threadIdx.x, w = tid >> 6, lane = tid & 63;

    // tnorm weight softmax (uniform, trivial)
    const float t0 = tw[0], t1 = tw[1], t2 = tw[2];
    const float mx3 = fmaxf(t0, fmaxf(t1, t2));
    const float e0 = expf(t0-mx3), e1 = expf(t1-mx3), e2 = expf(t2-mx3);
    const float inv3 = 1.0f / (e0+e1+e2);
    const float w0 = e0*inv3, w1 = e1*inv3, w2 = e2*inv3;

    // km -> registers: this lane's 8 j's, 5 features each
    float kr[8][F_];
#pragma unroll
    for (int jj = 0; jj < 8; ++jj) {
        const size_t kb = ((size_t)bh*S_ + jj*64 + lane)*F_;
#pragma unroll
        for (int f = 0; f < F_; ++f) kr[jj][f] = km[kb + f];
    }

    // --- score phase: 16 rows per wave ---
    for (int rl = 0; rl < 16; ++rl) {
        const int i = w*16 + rl;                       // local row 0..63
        const size_t qb = ((size_t)bh*S_ + s0 + i)*F_;
        const float q0 = qm[qb], q1 = qm[qb+1], q2 = qm[qb+2],
                    q3 = qm[qb+3], q4 = qm[qb+4];
        float s[8];
        float m = -INFINITY;
#pragma unroll
        for (int jj = 0; jj < 8; ++jj) {
            const float *kk = kr[jj];
            float prod = q0*kk[0] + q1*kk[1] + q2*kk[2] + q3*kk[3] + q4*kk[4];
            float mn = fminf(q0,kk[0]) + fminf(q1,kk[1]) + fminf(q2,kk[2])
                     + fminf(q3,kk[3]) + fminf(q4,kk[4]);
            float lk = fmaxf(q0+kk[0]-1.f,0.f) + fmaxf(q1+kk[1]-1.f,0.f)
                     + fmaxf(q2+kk[2]-1.f,0.f) + fmaxf(q3+kk[3]-1.f,0.f)
                     + fmaxf(q4+kk[4]-1.f,0.f);
            s[jj] = w0*prod + w1*mn + w2*lk;
            m = fmaxf(m, s[jj]);
        }
#pragma unroll
        for (int off = 32; off > 0; off >>= 1) m = fmaxf(m, __shfl_xor(m, off, 64));
        float e[8], sum = 0.f;
#pragma unroll
        for (int jj = 0; jj < 8; ++jj) { e[jj] = expf(s[jj]-m); sum += e[jj]; }
#pragma unroll
        for (int off = 32; off > 0; off >>= 1) sum += __shfl_xor(sum, off, 64);
        const float invs = 1.0f / sum;
#pragma unroll
        for (int jj = 0; jj < 8; ++jj) {
            const float a = e[jj]*invs;
            attn[((size_t)(bh*S_ + s0 + i))*S_ + jj*64 + lane] = a;
            const int byte = i*1024 + (jj*64 + lane)*2;
            *reinterpret_cast<short*>(
                reinterpret_cast<char*>(P) + (byte ^ ((i&7)<<4))) = f2bf(a);
        }
    }
    __syncthreads();

    // --- PV phase: wave w owns rows [w*16, w*16+16), all 64 hd ---
    const short* __restrict__ Vb = vT + (size_t)bh*HD_*S_;
    f32x4 acc[4] = {};
    const int arow = w*16 + (lane & 15);
    const int asw  = (arow & 7) << 4;
#pragma unroll
    for (int ks = 0; ks < 16; ++ks) {
        const int abyte = arow*1024 + ks*64 + (lane>>4)*16;
        const bf16x8 a = *reinterpret_cast<const bf16x8*>(
            reinterpret_cast<const char*>(P) + (abyte ^ asw));
#pragma unroll
        for (int f = 0; f < 4; ++f) {
            const bf16x8 b = *reinterpret_cast<const bf16x8*>(
                &Vb[(size_t)(f*16 + (lane & 15))*S_ + ks*32 + (lane>>4)*8]);
            acc[f] = __builtin_amdgcn_mfma_f32_16x16x32_bf16(a, b, acc[f], 0, 0, 0);
        }
    }
    const int b_ = bh >> 3, h = bh & 7;
#pragma unroll
    for (int f = 0; f < 4; ++f)
#pragma unroll
        for (int r = 0; r < 4; ++r) {
            const int s = s0 + w*16 + (lane>>4)*4 + r;
            ctx[((size_t)(b_*S_ + s))*D_ + h*HD_ + f*16 + (lane & 15)] = acc[f][r];
        }
}

// ---------------------------------------------------------------------------
// K3: out = ctx(2048x512) @ Wo + bo.  64x64 tile, 4 waves (2x2), wave 32x32.
// A = ctx f32 (reg-stage + convert), B = WoT bf16 (global_load_lds).
// ---------------------------------------------------------------------------
__global__ __launch_bounds__(256) void out_mfma(
    const float* __restrict__ ctx, const short* __restrict__ WoT,
    const float* __restrict__ bo, float* __restrict__ out)
{
    const int m0 = blockIdx.x * 64;
    const int n0 = blockIdx.y * 64;

    __shared__ short As[64*64];
    __shared__ short Bs[64*64];
    const int tid = threadIdx.x;
    const int wid = tid >> 6, lane = tid & 63;
    const int wr = wid >> 1, wc = wid & 1;

    f32x4 acc[2][2] = {};

    for (int k0 = 0; k0 < D_; k0 += 64) {
#pragma unroll
        for (int i = 0; i < 2; ++i) {
            const int c = wid*2 + i;
            const int row = c*8 + (lane >> 3);
            const int kk  = (lane & 7) * 8;
            GLOAD16(&Bs[c*512], &WoT[(size_t)(n0+row)*D_ + k0 + kk]);
        }
#pragma unroll
        for (int hf = 0; hf < 2; ++hf) {
            const int tt = tid + hf*256;
            const int row = tt >> 3, kk = (tt & 7) * 8;
            const float* p = &ctx[(size_t)(m0+row)*D_ + k0 + kk];
            float4 fa = *reinterpret_cast<const float4*>(p);
            float4 fb = *reinterpret_cast<const float4*>(p+4);
            bf16x8 pk;
            pk[0]=f2bf(fa.x); pk[1]=f2bf(fa.y); pk[2]=f2bf(fa.z); pk[3]=f2bf(fa.w);
            pk[4]=f2bf(fb.x); pk[5]=f2bf(fb.y); pk[6]=f2bf(fb.z); pk[7]=f2bf(fb.w);
            *reinterpret_cast<bf16x8*>(&As[tt*8]) = pk;
        }
        asm volatile("s_waitcnt vmcnt(0)" ::: "memory");
        __syncthreads();
#pragma unroll
        for (int ks = 0; ks < 2; ++ks) {
            bf16x8 a[2], b[2];
#pragma unroll
            for (int f = 0; f < 2; ++f) {
                const int ar = wr*32 + f*16 + (lane & 15);
                a[f] = *reinterpret_cast<const bf16x8*>(&As[ar*64 + ks*32 + (lane>>4)*8]);
                const int br = wc*32 + f*16 + (lane & 15);
                b[f] = *reinterpret_cast<const bf16x8*>(&Bs[br*64 + ks*32 + (lane>>4)*8]);
            }
#pragma unroll
            for (int i = 0; i < 2; ++i)
#pragma unroll
                for (int j = 0; j < 2; ++j)
                    acc[i][j] = __builtin_amdgcn_mfma_f32_16x16x32_bf16(a[i], b[j], acc[i][j], 0, 0, 0);
        }
        __syncthreads();
    }
#pragma unroll
    for (int i = 0; i < 2; ++i)
#pragma unroll
        for (int j = 0; j < 2; ++j)
#pragma unroll
            for (int r = 0; r < 4; ++r) {
                const int m = m0 + wr*32 + i*16 + (lane>>4)*4 + r;
                const int n = n0 + wc*32 + j*16 + (lane & 15);
                out[(size_t)m*D_ + n] = acc[i][j][r] + bo[n];
            }
}

// ---------------------------------------------------------------------------
extern "C" void kernel_launch(void* const* d_in, const int* in_sizes, int n_in,
                              void* d_out, int out_size, void* d_ws, size_t ws_size,
                              hipStream_t stream)
{
    const float* x  = (const float*)d_in[0];
    const float* Wq = (const float*)d_in[1];
    const float* bq = (const float*)d_in[2];
    const float* Wk = (const float*)d_in[3];
    const float* bk = (const float*)d_in[4];
    const float* Wv = (const float*)d_in[5];
    const float* bv = (const float*)d_in[6];
    const float* Wo = (const float*)d_in[7];
    const float* bo = (const float*)d_in[8];
    const float* gc = (const float*)d_in[9];
    const float* gs = (const float*)d_in[10];
    const float* gw = (const float*)d_in[11];
    const float* tw = (const float*)d_in[12];

    short* xb    = (short*)d_ws;                      // 1,048,576 bf16
    short* WqkvT = xb + 1048576;                      //   786,432 bf16
    short* WoT   = WqkvT + 786432;                    //   262,144 bf16
    short* vT    = WoT + 262144;                      // 1,048,576 bf16
    float* qm    = (float*)(vT + 1048576);            //    81,920 f32
    float* km    = qm + 81920;                        //    81,920 f32
    float* ctx   = km + 81920;                        // 1,048,576 f32

    float* out0 = (float*)d_out;                      // (B,S,D)
    float* attn = out0 + (size_t)B_*S_*D_;            // (B,H,S,S)

    convert_fused<<<1280, 256, 0, stream>>>(x, Wq, Wk, Wv, Wo, xb, WqkvT, WoT);
    qkv_mfma<<<dim3(NROW/128, 1536/128), 256, 0, stream>>>(
        xb, WqkvT, bq, bk, bv, gc, gs, gw, qm, km, vT);
    scores_av<<<dim3(S_/64, B_*H_), 256, 0, stream>>>(qm, km, tw, vT, attn, ctx);
    out_mfma<<<dim3(NROW/64, D_/64), 256, 0, stream>>>(ctx, WoT, bo, out0);
}

// Round 4
// 55.335 us; speedup vs baseline: 2.4293x; 1.3924x over previous
//
#include <hip/hip_runtime.h>
#include <hip/hip_bf16.h>

#define B_  4
#define S_  512
#define D_  512
#define H_  8
#define HD_ 64
#define F_  5
#define NROW (B_*S_)     // 2048
#define BHS  (B_*H_*S_)  // 16384
#define EPS_ 1e-8f

typedef __attribute__((ext_vector_type(8))) short bf16x8;
typedef __attribute__((ext_vector_type(4))) float f32x4;

static __device__ __forceinline__ short f2bf(float f) {
    __hip_bfloat16 h = __float2bfloat16(f);
    return *reinterpret_cast<short*>(&h);
}

// async global->LDS, 16B per lane; dest = ldsbase + lane*16 (wave-linear)
#define GLOAD16(ldsp, gp) \
    __builtin_amdgcn_global_load_lds( \
        (const __attribute__((address_space(1))) unsigned int*)(gp), \
        (__attribute__((address_space(3))) unsigned int*)(ldsp), 16, 0, 0)

// ---------------------------------------------------------------------------
// C1: merged conversions.
//   blocks [0,1024):   x f32 -> xb bf16 (same layout)
//   blocks [1024,1280): Wq/Wk/Wv/Wo f32 (k-major) -> WqkvT[1536][512] /
//                       WoT[512][512] bf16 (n-major)
// ---------------------------------------------------------------------------
__global__ __launch_bounds__(256) void convert_fused(
    const float* __restrict__ x,
    const float* __restrict__ Wq, const float* __restrict__ Wk,
    const float* __restrict__ Wv, const float* __restrict__ Wo,
    short* __restrict__ xb, short* __restrict__ WqkvT, short* __restrict__ WoT)
{
    const int bid = blockIdx.x;
    if (bid < 1024) {
        int i = bid * 256 + threadIdx.x;          // 262144 float4s exactly
        float4 f = reinterpret_cast<const float4*>(x)[i];
        short4 o;
        o.x = f2bf(f.x); o.y = f2bf(f.y); o.z = f2bf(f.z); o.w = f2bf(f.w);
        reinterpret_cast<short4*>(xb)[i] = o;
        return;
    }
    const int wb = bid - 1024;
    const int widx = wb >> 6;                  // 0..3
    const int tile = wb & 63;                  // 8x8 tiles of 64x64
    const int k0 = (tile >> 3) * 64, n0 = (tile & 7) * 64;
    const float* __restrict__ src = widx==0?Wq:(widx==1?Wk:(widx==2?Wv:Wo));
    short* __restrict__ dst = (widx < 3) ? WqkvT : WoT;
    const int drow0 = (widx < 3) ? widx * 512 : 0;

    __shared__ short T[64][72];
    const int t = threadIdx.x;
    const int r = t >> 2, qq = t & 3;
#pragma unroll
    for (int i = 0; i < 4; ++i) {
        float4 f = *reinterpret_cast<const float4*>(&src[(k0+r)*D_ + n0 + qq*16 + i*4]);
        T[r][qq*16+i*4+0] = f2bf(f.x);
        T[r][qq*16+i*4+1] = f2bf(f.y);
        T[r][qq*16+i*4+2] = f2bf(f.z);
        T[r][qq*16+i*4+3] = f2bf(f.w);
    }
    __syncthreads();
    const int c = t >> 2;                       // local n
#pragma unroll
    for (int i = 0; i < 4; ++i) {
        short4 o;
        o.x = T[qq*16+i*4+0][c];
        o.y = T[qq*16+i*4+1][c];
        o.z = T[qq*16+i*4+2][c];
        o.w = T[qq*16+i*4+3][c];
        *reinterpret_cast<short4*>(&dst[(size_t)(drow0+n0+c)*512 + k0 + qq*16 + i*4]) = o;
    }
}

// ---------------------------------------------------------------------------
// K1: QKV MFMA GEMM + fused membership (q,k) + fused vT write (v).
// xb(2048x512) @ WqkvT(1536x512 n-major).  64x128 tile, BK=64, 4 waves (2x2),
// wave = 32x64.  Grid 32x12 = 384 blocks (all CUs busy).
// ---------------------------------------------------------------------------
__global__ __launch_bounds__(256) void qkv_mfma(
    const short* __restrict__ Ab, const short* __restrict__ BT,
    const float* __restrict__ bq, const float* __restrict__ bk,
    const float* __restrict__ bv,
    const float* __restrict__ gc, const float* __restrict__ gs,
    const float* __restrict__ gw,
    float* __restrict__ qm, float* __restrict__ km, short* __restrict__ vT)
{
    __shared__ short As[64*64];    // [m][k] 8KB  (8 chunks of 1KB)
    __shared__ short Bs[128*64];   // [n][k] 16KB (16 chunks)
    const int tid = threadIdx.x;
    const int wid = tid >> 6, lane = tid & 63;
    const int wr = wid >> 1, wc = wid & 1;
    const int m0 = blockIdx.x * 64, n0 = blockIdx.y * 128;

    f32x4 acc[2][4] = {};

    for (int k0 = 0; k0 < 512; k0 += 64) {
        // A: 8 chunks, 2 per wave
#pragma unroll
        for (int i = 0; i < 2; ++i) {
            const int c = wid*2 + i;
            const int row = c*8 + (lane >> 3);
            const int kk  = (lane & 7) * 8;
            GLOAD16(&As[c*512], &Ab[(size_t)(m0+row)*512 + k0 + kk]);
        }
        // B: 16 chunks, 4 per wave
#pragma unroll
        for (int i = 0; i < 4; ++i) {
            const int c = wid*4 + i;
            const int row = c*8 + (lane >> 3);
            const int kk  = (lane & 7) * 8;
            GLOAD16(&Bs[c*512], &BT[(size_t)(n0+row)*512 + k0 + kk]);
        }
        asm volatile("s_waitcnt vmcnt(0)" ::: "memory");
        __syncthreads();
#pragma unroll
        for (int ks = 0; ks < 2; ++ks) {
            bf16x8 a[2], b[4];
#pragma unroll
            for (int f = 0; f < 2; ++f) {
                const int ar = wr*32 + f*16 + (lane & 15);
                a[f] = *reinterpret_cast<const bf16x8*>(&As[ar*64 + ks*32 + (lane>>4)*8]);
            }
#pragma unroll
            for (int f = 0; f < 4; ++f) {
                const int br = wc*64 + f*16 + (lane & 15);
                b[f] = *reinterpret_cast<const bf16x8*>(&Bs[br*64 + ks*32 + (lane>>4)*8]);
            }
#pragma unroll
            for (int i = 0; i < 2; ++i)
#pragma unroll
                for (int j = 0; j < 4; ++j)
                    acc[i][j] = __builtin_amdgcn_mfma_f32_16x16x32_bf16(a[i], b[j], acc[i][j], 0, 0, 0);
        }
        __syncthreads();
    }

    const int wsel = n0 >> 9;              // 0:q 1:k 2:v
    const int h = ((n0 & 511) >> 6) + wc;  // head this wave owns (64 cols)
    const int b_ = m0 >> 9;                // batch (64-tile never straddles)
    const int bh = b_*H_ + h;
    const int hdl = lane & 15;

    if (wsel < 2) {
        // ---- fused Gaussian membership ----
        const float* __restrict__ bias = wsel==0 ? bq : bk;
        float* __restrict__ dst        = wsel==0 ? qm : km;
        float gcv[F_][4], isv[F_][4], bi4[4];
#pragma unroll
        for (int f = 0; f < F_; ++f)
#pragma unroll
            for (int j = 0; j < 4; ++j) {
                const int hd = j*16 + hdl;
                gcv[f][j] = gc[f*HD_ + hd];
                isv[f][j] = 1.0f / (gs[f*HD_ + hd] + EPS_);
            }
#pragma unroll
        for (int j = 0; j < 4; ++j) bi4[j] = bias[h*64 + j*16 + hdl];
        float gwv[F_];
#pragma unroll
        for (int f = 0; f < F_; ++f) gwv[f] = gw[f];

#pragma unroll
        for (int i = 0; i < 2; ++i)
#pragma unroll
            for (int r = 0; r < 4; ++r) {
                float z[4];
#pragma unroll
                for (int j = 0; j < 4; ++j) z[j] = acc[i][j][r] + bi4[j];
                float p[F_];
#pragma unroll
                for (int f = 0; f < F_; ++f) {
                    float t = 0.f;
#pragma unroll
                    for (int j = 0; j < 4; ++j) {
                        const float nd = (z[j] - gcv[f][j]) * isv[f][j];
                        t = fmaf(nd*nd, -0.5f, t);
                    }
                    p[f] = t;
                }
#pragma unroll
                for (int off = 1; off < 16; off <<= 1)
#pragma unroll
                    for (int f = 0; f < F_; ++f) p[f] += __shfl_xor(p[f], off, 64);
                if (hdl == 0) {
                    const int m = m0 + wr*32 + i*16 + (lane>>4)*4 + r;
                    const int s = m & 511;
                    float* o = &dst[((size_t)bh*S_ + s)*F_];
#pragma unroll
                    for (int f = 0; f < F_; ++f) o[f] = expf(p[f]) * gwv[f];
                }
            }
    } else {
        // ---- fused V transpose: vT[bh][hd][s] bf16 ----
        float bi4[4];
#pragma unroll
        for (int j = 0; j < 4; ++j) bi4[j] = bv[h*64 + j*16 + hdl];
#pragma unroll
        for (int i = 0; i < 2; ++i)
#pragma unroll
            for (int j = 0; j < 4; ++j) {
                short4 o;
                o.x = f2bf(acc[i][j][0] + bi4[j]);
                o.y = f2bf(acc[i][j][1] + bi4[j]);
                o.z = f2bf(acc[i][j][2] + bi4[j]);
                o.w = f2bf(acc[i][j][3] + bi4[j]);
                const int sb = (m0 & 511) + wr*32 + i*16 + (lane>>4)*4;
                *reinterpret_cast<short4*>(
                    &vT[((size_t)bh*HD_ + j*16 + hdl)*S_ + sb]) = o;
            }
    }
}

// ---------------------------------------------------------------------------
// K2: fused scores + softmax + attn-write + PV MFMA.
// Block = (32-row tile, bh), grid (16,32)=512 blocks, 4 waves.
// qm staged in LDS (broadcast reads); km in registers; P in 32KB swizzled LDS;
// V from global (L2-resident).  ctx written as bf16.
// ---------------------------------------------------------------------------
__global__ __launch_bounds__(256) void scores_av(
    const float* __restrict__ qm, const float* __restrict__ km,
    const float* __restrict__ tw, const short* __restrict__ vT,
    float* __restrict__ attn, short* __restrict__ ctxb)
{
    __shared__ float qs[32*F_];            // 640B
    __shared__ short P[32*512];            // 32KB, [row][j] with byte^=(row&7)<<4
    const int s0 = blockIdx.x * 32;
    const int bh = blockIdx.y;
    const int tid = threadIdx.x, w = tid >> 6, lane = tid & 63;

    // tnorm weight softmax (uniform, trivial)
    const float t0 = tw[0], t1 = tw[1], t2 = tw[2];
    const float mx3 = fmaxf(t0, fmaxf(t1, t2));
    const float e0 = __expf(t0-mx3), e1 = __expf(t1-mx3), e2 = __expf(t2-mx3);
    const float inv3 = 1.0f / (e0+e1+e2);
    const float w0 = e0*inv3, w1 = e1*inv3, w2 = e2*inv3;

    // qm tile -> LDS (one coalesced load)
    if (tid < 32*F_) qs[tid] = qm[((size_t)bh*S_ + s0)*F_ + tid];

    // km -> registers: this lane's 8 j's, 5 features each
    float kr[8][F_];
#pragma unroll
    for (int jj = 0; jj < 8; ++jj) {
        const size_t kb = ((size_t)bh*S_ + jj*64 + lane)*F_;
#pragma unroll
        for (int f = 0; f < F_; ++f) kr[jj][f] = km[kb + f];
    }
    __syncthreads();

    // --- score phase: 8 rows per wave, unroll 2 for ILP ---
#pragma unroll 2
    for (int rl = 0; rl < 8; ++rl) {
        const int i = w*8 + rl;                        // local row 0..31
        const float q0 = qs[i*F_+0], q1 = qs[i*F_+1], q2 = qs[i*F_+2],
                    q3 = qs[i*F_+3], q4 = qs[i*F_+4];
        float s[8];
        float m = -INFINITY;
#pragma unroll
        for (int jj = 0; jj < 8; ++jj) {
            const float *kk = kr[jj];
            float prod = q0*kk[0] + q1*kk[1] + q2*kk[2] + q3*kk[3] + q4*kk[4];
            float mn = fminf(q0,kk[0]) + fminf(q1,kk[1]) + fminf(q2,kk[2])
                     + fminf(q3,kk[3]) + fminf(q4,kk[4]);
            float lk = fmaxf(q0+kk[0]-1.f,0.f) + fmaxf(q1+kk[1]-1.f,0.f)
                     + fmaxf(q2+kk[2]-1.f,0.f) + fmaxf(q3+kk[3]-1.f,0.f)
                     + fmaxf(q4+kk[4]-1.f,0.f);
            s[jj] = w0*prod + w1*mn + w2*lk;
            m = fmaxf(m, s[jj]);
        }
#pragma unroll
        for (int off = 32; off > 0; off >>= 1) m = fmaxf(m, __shfl_xor(m, off, 64));
        float e[8], sum = 0.f;
#pragma unroll
        for (int jj = 0; jj < 8; ++jj) { e[jj] = __expf(s[jj]-m); sum += e[jj]; }
#pragma unroll
        for (int off = 32; off > 0; off >>= 1) sum += __shfl_xor(sum, off, 64);
        const float invs = 1.0f / sum;
#pragma unroll
        for (int jj = 0; jj < 8; ++jj) {
            const float a = e[jj]*invs;
            attn[((size_t)(bh*S_ + s0 + i))*S_ + jj*64 + lane] = a;
            const int byte = i*1024 + (jj*64 + lane)*2;
            *reinterpret_cast<short*>(
                reinterpret_cast<char*>(P) + (byte ^ ((i&7)<<4))) = f2bf(a);
        }
    }
    __syncthreads();

    // --- PV phase: wave = (16-row half h0) x (32-hd half f0*16) ---
    const short* __restrict__ Vb = vT + (size_t)bh*HD_*S_;
    const int h0 = (w & 1) * 16;
    const int f0 = (w >> 1) * 2;
    f32x4 acc[2] = {};
    const int arow = h0 + (lane & 15);
    const int asw  = (arow & 7) << 4;
#pragma unroll
    for (int ks = 0; ks < 16; ++ks) {
        const int abyte = arow*1024 + ks*64 + (lane>>4)*16;
        const bf16x8 a = *reinterpret_cast<const bf16x8*>(
            reinterpret_cast<const char*>(P) + (abyte ^ asw));
#pragma unroll
        for (int ff = 0; ff < 2; ++ff) {
            const bf16x8 b = *reinterpret_cast<const bf16x8*>(
                &Vb[(size_t)((f0+ff)*16 + (lane & 15))*S_ + ks*32 + (lane>>4)*8]);
            acc[ff] = __builtin_amdgcn_mfma_f32_16x16x32_bf16(a, b, acc[ff], 0, 0, 0);
        }
    }
    const int b_ = bh >> 3, h = bh & 7;
#pragma unroll
    for (int ff = 0; ff < 2; ++ff)
#pragma unroll
        for (int r = 0; r < 4; ++r) {
            const int s = s0 + h0 + (lane>>4)*4 + r;
            ctxb[((size_t)(b_*S_ + s))*D_ + h*HD_ + (f0+ff)*16 + (lane & 15)]
                = f2bf(acc[ff][r]);
        }
}

// ---------------------------------------------------------------------------
// K3: out = ctxb(2048x512 bf16) @ WoT + bo.  64x64 tile, 4 waves, wave 32x32.
// Both A and B staged via global_load_lds (no reg-stage conversion).
// ---------------------------------------------------------------------------
__global__ __launch_bounds__(256) void out_mfma(
    const short* __restrict__ ctxb, const short* __restrict__ WoT,
    const float* __restrict__ bo, float* __restrict__ out)
{
    const int m0 = blockIdx.x * 64;
    const int n0 = blockIdx.y * 64;

    __shared__ short As[64*64];
    __shared__ short Bs[64*64];
    const int tid = threadIdx.x;
    const int wid = tid >> 6, lane = tid & 63;
    const int wr = wid >> 1, wc = wid & 1;

    f32x4 acc[2][2] = {};

    for (int k0 = 0; k0 < D_; k0 += 64) {
#pragma unroll
        for (int i = 0; i < 2; ++i) {
            const int c = wid*2 + i;
            const int row = c*8 + (lane >> 3);
            const int kk  = (lane & 7) * 8;
            GLOAD16(&As[c*512], &ctxb[(size_t)(m0+row)*D_ + k0 + kk]);
            GLOAD16(&Bs[c*512], &WoT[(size_t)(n0+row)*D_ + k0 + kk]);
        }
        asm volatile("s_waitcnt vmcnt(0)" ::: "memory");
        __syncthreads();
#pragma unroll
        for (int ks = 0; ks < 2; ++ks) {
            bf16x8 a[2], b[2];
#pragma unroll
            for (int f = 0; f < 2; ++f) {
                const int ar = wr*32 + f*16 + (lane & 15);
                a[f] = *reinterpret_cast<const bf16x8*>(&As[ar*64 + ks*32 + (lane>>4)*8]);
                const int br = wc*32 + f*16 + (lane & 15);
                b[f] = *reinterpret_cast<const bf16x8*>(&Bs[br*64 + ks*32 + (lane>>4)*8]);
            }
#pragma unroll
            for (int i = 0; i < 2; ++i)
#pragma unroll
                for (int j = 0; j < 2; ++j)
                    acc[i][j] = __builtin_amdgcn_mfma_f32_16x16x32_bf16(a[i], b[j], acc[i][j], 0, 0, 0);
        }
        __syncthreads();
    }
#pragma unroll
    for (int i = 0; i < 2; ++i)
#pragma unroll
        for (int j = 0; j < 2; ++j)
#pragma unroll
            for (int r = 0; r < 4; ++r) {
                const int m = m0 + wr*32 + i*16 + (lane>>4)*4 + r;
                const int n = n0 + wc*32 + j*16 + (lane & 15);
                out[(size_t)m*D_ + n] = acc[i][j][r] + bo[n];
            }
}

// ---------------------------------------------------------------------------
extern "C" void kernel_launch(void* const* d_in, const int* in_sizes, int n_in,
                              void* d_out, int out_size, void* d_ws, size_t ws_size,
                              hipStream_t stream)
{
    const float* x  = (const float*)d_in[0];
    const float* Wq = (const float*)d_in[1];
    const float* bq = (const float*)d_in[2];
    const float* Wk = (const float*)d_in[3];
    const float* bk = (const float*)d_in[4];
    const float* Wv = (const float*)d_in[5];
    const float* bv = (const float*)d_in[6];
    const float* Wo = (const float*)d_in[7];
    const float* bo = (const float*)d_in[8];
    const float* gc = (const float*)d_in[9];
    const float* gs = (const float*)d_in[10];
    const float* gw = (const float*)d_in[11];
    const float* tw = (const float*)d_in[12];

    short* xb    = (short*)d_ws;                      // 1,048,576 bf16
    short* WqkvT = xb + 1048576;                      //   786,432 bf16
    short* WoT   = WqkvT + 786432;                    //   262,144 bf16
    short* vT    = WoT + 262144;                      // 1,048,576 bf16
    short* ctxb  = vT + 1048576;                      // 1,048,576 bf16
    float* qm    = (float*)(ctxb + 1048576);          //    81,920 f32
    float* km    = qm + 81920;                        //    81,920 f32

    float* out0 = (float*)d_out;                      // (B,S,D)
    float* attn = out0 + (size_t)B_*S_*D_;            // (B,H,S,S)

    convert_fused<<<1280, 256, 0, stream>>>(x, Wq, Wk, Wv, Wo, xb, WqkvT, WoT);
    qkv_mfma<<<dim3(NROW/64, 1536/128), 256, 0, stream>>>(
        xb, WqkvT, bq, bk, bv, gc, gs, gw, qm, km, vT);
    scores_av<<<dim3(S_/32, B_*H_), 256, 0, stream>>>(qm, km, tw, vT, attn, ctxb);
    out_mfma<<<dim3(NROW/64, D_/64), 256, 0, stream>>>(ctxb, WoT, bo, out0);
}